// Round 6
// baseline (165.388 us; speedup 1.0000x reference)
//
#include <hip/hip_runtime.h>
#include <stdint.h>

#define N_ROWS 4096
#define N_DIM  2048
#define MARGIN 0.3f
#define NTILE  32            // 4096 / 128 col-tiles
#define NSTEP  64            // K steps of BK=32
#define FLTMAX 3.402823466e+38f

typedef __attribute__((ext_vector_type(8))) short short8;
typedef __attribute__((ext_vector_type(4))) float floatx4;

// Packed layout ("fragment order"): for 16-row group b (256 total) and k-chunk
// c (32 k, 64 total), a 1 KB block at shorts-offset (b*64+c)*512. Lane l's
// 16 B fragment at l*8 shorts = row b*16+(l&15), k c*32+(l>>4)*8.. (verified
// absmax 0.0 in R1-R5).

__device__ inline unsigned short f2bf_rne(float f) {
  unsigned u = __float_as_uint(f);
  unsigned r = 0x7fffu + ((u >> 16) & 1u);
  return (unsigned short)((u + r) >> 16);
}
__device__ inline float bf2f(unsigned short h) {
  return __uint_as_float(((unsigned)h) << 16);
}

// ---------------------------------------------------------------------------
// Kernel 1: cast fp32 -> bf16 AND repack into fragment order; sq[i] from the
// ROUNDED values; init per-row reduction cells. One block per 16-row group.
// ---------------------------------------------------------------------------
__global__ __launch_bounds__(256) void prep_kernel(
    const float* __restrict__ X, unsigned short* __restrict__ Xp,
    float* __restrict__ sq, unsigned* __restrict__ ap, unsigned* __restrict__ an)
{
  const int b = blockIdx.x;
  const int t = threadIdx.x;
  const int r = t & 15, j = (t >> 4) & 3, w = t >> 6;
  const float* Xg = X + ((size_t)b * 16 + r) * N_DIM + j * 8;
  unsigned short* Op = Xp + (size_t)b * 64 * 512 + (size_t)(j * 16 + r) * 8;
  float acc = 0.f;
#pragma unroll
  for (int s = 0; s < 16; ++s) {
    const int c = w + s * 4;
    float4 v0 = *(const float4*)(Xg + c * 32);
    float4 v1 = *(const float4*)(Xg + c * 32 + 4);
    short8 o;
    o[0] = (short)f2bf_rne(v0.x); o[1] = (short)f2bf_rne(v0.y);
    o[2] = (short)f2bf_rne(v0.z); o[3] = (short)f2bf_rne(v0.w);
    o[4] = (short)f2bf_rne(v1.x); o[5] = (short)f2bf_rne(v1.y);
    o[6] = (short)f2bf_rne(v1.z); o[7] = (short)f2bf_rne(v1.w);
#pragma unroll
    for (int e = 0; e < 8; ++e) {
      float f = bf2f((unsigned short)o[e]);
      acc = fmaf(f, f, acc);
    }
    *(short8*)(Op + (size_t)c * 512) = o;
  }
  acc += __shfl_xor(acc, 16, 64);
  acc += __shfl_xor(acc, 32, 64);
  __shared__ float part[4][16];
  if ((t & 63) < 16) part[w][r] = acc;
  __syncthreads();
  if (t < 16) {
    float s4 = part[0][t] + part[1][t] + part[2][t] + part[3][t];
    sq[b * 16 + t] = s4;
    ap[b * 16 + t] = 0u;           // max identity (dist >= 0)
    an[b * 16 + t] = 0x7f7fffffu;  // FLT_MAX bits
  }
}

// ---------------------------------------------------------------------------
// Kernel 2: 64x128 blocks (2 waves, wave tile 64x64) over upper-triangle
// 128x128 pair-tiles half-split (R3 geometry, grid 1056). Fragments loaded
// straight from packed global (1 KB coalesced dwordx4), BK=32 ping-pong
// (8-frag batches, 64 frag regs), no K-loop barriers. __launch_bounds__(128,3)
// caps regs at ~170 -> 12 waves/CU capacity: ALL blocks resident, no rounds.
// Each wave's 64x64 output feeds row-side AND (symmetry) col-side reductions.
// ---------------------------------------------------------------------------
__global__ __launch_bounds__(128, 3) void dist_kernel(
    const unsigned short* __restrict__ Xp, const float* __restrict__ sq,
    const int* __restrict__ lab, unsigned* __restrict__ ap, unsigned* __restrict__ an)
{
  __shared__ float sqi[64], sqj[128];
  __shared__ int labi[64], labj[128];

  // decode: pair p (bi<=bj over 32 col-tiles) + half h (64-row band)
  int p = blockIdx.x >> 1;
  const int h = blockIdx.x & 1;
  int bi = 0;
  while (p >= NTILE - bi) { p -= NTILE - bi; ++bi; }
  const int bj = bi + p;

  const int t = threadIdx.x;
  const int lane = t & 63, wn = t >> 6;    // 2 waves; wave wn = cols [wn*64, wn*64+64)

  { int cc = bj * 128 + t; sqj[t] = sq[cc]; labj[t] = lab[cc]; }
  if (t < 64) { int rr = bi * 128 + h * 64 + t; sqi[t] = sq[rr]; labi[t] = lab[rr]; }
  __syncthreads();   // once; K-loop below is barrier-free

  // fragment base offsets (in shorts); step s adds s*512
  unsigned aoff[4], boff[4];
#pragma unroll
  for (int mi = 0; mi < 4; ++mi)
    aoff[mi] = (unsigned)((bi * 8 + h * 4 + mi) * 64) * 512 + lane * 8;
#pragma unroll
  for (int ni = 0; ni < 4; ++ni)
    boff[ni] = (unsigned)((bj * 8 + wn * 4 + ni) * 64) * 512 + lane * 8;

  short8 fa[2][4], fb[2][4];   // ping-pong, 64 regs total
#pragma unroll
  for (int mi = 0; mi < 4; ++mi) fa[0][mi] = *(const short8*)(Xp + aoff[mi]);
#pragma unroll
  for (int ni = 0; ni < 4; ++ni) fb[0][ni] = *(const short8*)(Xp + boff[ni]);

  floatx4 acc[4][4] = {};

#pragma unroll 4
  for (int s = 0; s < NSTEP; ++s) {
    const int cb = s & 1;
    if (s + 1 < NSTEP) {
      const unsigned so = (unsigned)(s + 1) * 512;
#pragma unroll
      for (int mi = 0; mi < 4; ++mi)
        fa[cb ^ 1][mi] = *(const short8*)(Xp + aoff[mi] + so);
#pragma unroll
      for (int ni = 0; ni < 4; ++ni)
        fb[cb ^ 1][ni] = *(const short8*)(Xp + boff[ni] + so);
    }
#pragma unroll
    for (int mi = 0; mi < 4; ++mi)
#pragma unroll
      for (int ni = 0; ni < 4; ++ni)
        acc[mi][ni] = __builtin_amdgcn_mfma_f32_16x16x32_bf16(
            fa[cb][mi], fb[cb][ni], acc[mi][ni], 0, 0, 0);
  }

  // Epilogue. C/D layout (m89): col = lane&15, row = (lane>>4)*4 + reg.
  const int cn = lane & 15, lg = lane >> 4;
  float sqc[4]; int labc[4];
#pragma unroll
  for (int ni = 0; ni < 4; ++ni) {
    int c = wn * 64 + ni * 16 + cn;
    sqc[ni] = sqj[c]; labc[ni] = labj[c];
  }
  float cap[4] = {0.f, 0.f, 0.f, 0.f};
  float can[4] = {FLTMAX, FLTMAX, FLTMAX, FLTMAX};
#pragma unroll
  for (int mi = 0; mi < 4; ++mi) {
#pragma unroll
    for (int r = 0; r < 4; ++r) {
      const int rl = mi * 16 + lg * 4 + r;   // row within 64-row band
      const float si = sqi[rl];
      const int li = labi[rl];
      float apv = 0.0f;
      float anv = FLTMAX;
#pragma unroll
      for (int ni = 0; ni < 4; ++ni) {
        float g = acc[mi][ni][r];
        float d2 = fmaf(-2.0f, g, si + sqc[ni]);
        d2 = fmaxf(d2, 1e-12f);
        float d = __builtin_amdgcn_sqrtf(d2);
        const bool same = (li == labc[ni]);
        const float dp = same ? d : 0.0f;
        const float dn = same ? FLTMAX : d;
        apv = fmaxf(apv, dp);
        anv = fminf(anv, dn);
        cap[ni] = fmaxf(cap[ni], dp);   // col-side (symmetric) partials
        can[ni] = fminf(can[ni], dn);
      }
      // row side: reduce over the 16 cn-lanes (same lg = same row)
#pragma unroll
      for (int m = 8; m >= 1; m >>= 1) {
        apv = fmaxf(apv, __shfl_xor(apv, m, 64));
        anv = fminf(anv, __shfl_xor(anv, m, 64));
      }
      if (cn == 0) {
        int R = bi * 128 + h * 64 + rl;
        atomicMax(&ap[R], __float_as_uint(apv));
        atomicMin(&an[R], __float_as_uint(anv));
      }
    }
  }
  // col side: reduce over lg (xor 16,32) -> full 64 rows per column
#pragma unroll
  for (int ni = 0; ni < 4; ++ni) {
    float a = cap[ni], b = can[ni];
#pragma unroll
    for (int m = 16; m <= 32; m <<= 1) {
      a = fmaxf(a, __shfl_xor(a, m, 64));
      b = fminf(b, __shfl_xor(b, m, 64));
    }
    if (lg == 0) {
      int C = bj * 128 + wn * 64 + ni * 16 + cn;
      atomicMax(&ap[C], __float_as_uint(a));
      atomicMin(&an[C], __float_as_uint(b));
    }
  }
}

// ---------------------------------------------------------------------------
// Kernel 3: loss = mean(relu(margin + dist_ap - dist_an))
// ---------------------------------------------------------------------------
__global__ __launch_bounds__(256) void finalize_kernel(
    const unsigned* __restrict__ ap, const unsigned* __restrict__ an,
    float* __restrict__ out)
{
  const int t = threadIdx.x;
  float s = 0.f;
  for (int i = t; i < N_ROWS; i += 256) {
    float a = __uint_as_float(ap[i]);
    float b = __uint_as_float(an[i]);
    s += fmaxf(MARGIN + a - b, 0.0f);
  }
#pragma unroll
  for (int m = 32; m >= 1; m >>= 1) s += __shfl_down(s, m, 64);
  __shared__ float wsum[4];
  const int lane = t & 63, w = t >> 6;
  if (lane == 0) wsum[w] = s;
  __syncthreads();
  if (t == 0) out[0] = (wsum[0] + wsum[1] + wsum[2] + wsum[3]) * (1.0f / N_ROWS);
}

extern "C" void kernel_launch(void* const* d_in, const int* in_sizes, int n_in,
                              void* d_out, int out_size, void* d_ws, size_t ws_size,
                              hipStream_t stream) {
  const float* X = (const float*)d_in[0];
  const int* lab = (const int*)d_in[1];
  float* out = (float*)d_out;

  char* ws = (char*)d_ws;
  unsigned short* Xp = (unsigned short*)ws;                           // 16 MB packed
  float* sq  = (float*)(ws + (size_t)N_ROWS * N_DIM * 2);             // 16 KB
  unsigned* ap = (unsigned*)((char*)sq + N_ROWS * sizeof(float));     // 16 KB
  unsigned* an = (unsigned*)((char*)ap + N_ROWS * sizeof(unsigned));  // 16 KB

  prep_kernel<<<N_ROWS / 16, 256, 0, stream>>>(X, Xp, sq, ap, an);
  dist_kernel<<<NTILE * (NTILE + 1), 128, 0, stream>>>(Xp, sq, lab, ap, an);
  finalize_kernel<<<1, 256, 0, stream>>>(ap, an, out);
}